// Round 9
// baseline (157.299 us; speedup 1.0000x reference)
//
#include <hip/hip_runtime.h>
#include <cstdint>

typedef __attribute__((ext_vector_type(8))) short bf16x8;    // 8 bf16 = 4 VGPRs
typedef __attribute__((ext_vector_type(16))) float f32x16;   // 32x32 MFMA C/D
typedef __attribute__((ext_vector_type(4))) float f4;
typedef __attribute__((ext_vector_type(8))) unsigned short u16x8;
typedef unsigned short u16;

// JOURNAL:
// R9: 32x32x16 MFMA beats 16x16x32. R11/R12: ws aliasing abort -> fixed.
// R13 FAILED: 128^2 tile alone: 47.2us gemm12. R14 PARTIAL: 2-phase dbuf +
//      counted vmcnt(8): GEMMs ~41us each, 139.7 total.
// R16 BEST=137.7: + XCD supertile swizzle. ACCOUNTING: kernels ~95us; ~42us =
//      harness 256MiB ws re-poison (fillBuffer) in timed window — fixed cost.
// R17 FAILED (148.2): m97-parity single-buf gemm3 @4 blk/CU — full-drain
//      serializes; cross-block skew doesn't materialize at 8 K-iters.
// R18 NEUTRAL: 256^2 2-phase gemm3 still ~40us (halved staging traffic, same
//      time -> not L2-BW-bound either).
// R19/R20 NEUTRAL-WORSE: deep ring (4xBK=32, depth-3, counted vmcnt, setprio)
//      on gemm3 then gemm12: 142.5/148.3. gemm12-ring=42.5us measured (R19's
//      59us row = clock-throttled replay artifact; bytes/time = same 1.5TB/s).
// CONCLUSION R13-R20: EVERY schedule lands 41+-5us/GEMM (~470 TF) at these
//      shapes; MfmaUtil 16 / VALU 15 / HBM 19% all low = latency floor.
//      Schedule lever exhausted (matches m232 open quadrant, m102 shape curve).
// R21 (this round): revert to R16 exactly + ONE structural change: kill the
//      split-K partial round-trip. gemm3 epilogue = fp32 atomicAdd into out
//      (wave-coalesced 2x128B segs, ~131K wave-atomics ~2-3us) replacing
//      16.8MB part writes + reduce4 launch (~4.5us) + its 25MB traffic.
//      zero_out kernel (1.3us) first; stream order covers the dependency.
//      Numerics improve (fp32 partials, was bf16). Predict 137.7 -> ~132-135.
//      If gemm3 +5us (atomic storm): revert epilogue, accept R16.

__device__ __forceinline__ u16 f2bf(float f) {
  uint32_t u = __builtin_bit_cast(uint32_t, f);
  u += 0x7fffu + ((u >> 16) & 1u);          // round-to-nearest-even
  return (u16)(u >> 16);
}

__device__ __forceinline__ void async_cp16(const void* g, void* l) {
  __builtin_amdgcn_global_load_lds(
      (const __attribute__((address_space(1))) uint32_t*)g,
      (__attribute__((address_space(3))) uint32_t*)l, 16, 0, 0);
}

// zero the 4096x512 fp32 output (atomicAdd accumulation target). 8 elem/thread.
__global__ __launch_bounds__(256) void zero_out(float* __restrict__ out) {
  const int i = (blockIdx.x * 256 + threadIdx.x) * 8;
  f4 z = {0.f, 0.f, 0.f, 0.f};
  *(f4*)(out + i) = z;
  *(f4*)(out + i + 4) = z;
}

// cast x | features | prototypes -> contiguous bf16 region in ws (8 elem/thread)
__global__ __launch_bounds__(256) void cast3(
    const float* __restrict__ x, const float* __restrict__ f,
    const float* __restrict__ p, u16* __restrict__ dst,
    int n1, int n2, int n3) {
  int i = (blockIdx.x * 256 + threadIdx.x) * 8;
  const float* src;
  int local;
  if (i < n1) { src = x; local = i; }
  else if (i < n1 + n2) { src = f; local = i - n1; }
  else if (i < n1 + n2 + n3) { src = p; local = i - n1 - n2; }
  else return;
  f4 a = *(const f4*)(src + local);
  f4 b = *(const f4*)(src + local + 4);
  u16x8 o;
  o[0] = f2bf(a.x); o[1] = f2bf(a.y); o[2] = f2bf(a.z); o[3] = f2bf(a.w);
  o[4] = f2bf(b.x); o[5] = f2bf(b.y); o[6] = f2bf(b.z); o[7] = f2bf(b.w);
  *(u16x8*)(dst + i) = o;
}

// ---- 2-phase pipelined main loop (TM=128, TN=128, BK=64) — R14/R16 proven --
// C += A @ B^T with 32x32x16 MFMA. 16B-chunk XOR swizzle (0 bank conflicts).
// Wave grid 2x2: wave covers 64x64 = 2x2 acc tiles of 32x32.
// Next tile's 8 global_load_lds issued BEFORE compute; counted s_waitcnt
// vmcnt(8) + raw s_barrier keeps next-tile loads in flight across compute.

__device__ __forceinline__ void stage_tile(
    const u16* __restrict__ A, const u16* __restrict__ B, int K,
    int k0, int tid, u16* L) {
  constexpr int TM = 128, TN = 128;
  const int wave = tid >> 6;
  #pragma unroll
  for (int it = 0; it < TM / 32; ++it) {
    int c = it * 256 + tid;            // chunk index = LDS position
    int row = c >> 3, pc = c & 7;
    int gc = pc ^ (row & 7);           // which global 16B chunk lands here
    async_cp16(A + (size_t)row * K + (k0 + gc * 8),
               &L[(it * 256 + wave * 64) * 8]);
  }
  #pragma unroll
  for (int it = 0; it < TN / 32; ++it) {
    int c = it * 256 + tid;
    int row = c >> 3, pc = c & 7;
    int gc = pc ^ (row & 7);
    async_cp16(B + (size_t)row * K + (k0 + gc * 8),
               &L[TM * 64 + (it * 256 + wave * 64) * 8]);
  }
}

__device__ __forceinline__ void compute_tile(
    const u16* L, int lane, int wrow, int wcol, f32x16 (&acc)[2][2]) {
  constexpr int TM = 128;
  #pragma unroll
  for (int s = 0; s < 4; ++s) {        // 4 k-steps of K=16
    const int h = s * 2 + (lane >> 5); // 16B chunk along K this lane needs
    bf16x8 bfr[2], afr[2];
    #pragma unroll
    for (int j = 0; j < 2; ++j) {
      const int rb = wcol * 64 + j * 32 + (lane & 31);
      bfr[j] = *(const bf16x8*)&L[TM * 64 + (rb * 8 + (h ^ (rb & 7))) * 8];
    }
    #pragma unroll
    for (int i = 0; i < 2; ++i) {
      const int ra = wrow * 64 + i * 32 + (lane & 31);
      afr[i] = *(const bf16x8*)&L[(ra * 8 + (h ^ (ra & 7))) * 8];
    }
    #pragma unroll
    for (int i = 0; i < 2; ++i)
      #pragma unroll
      for (int j = 0; j < 2; ++j)
        acc[i][j] = __builtin_amdgcn_mfma_f32_32x32x16_bf16(
            afr[i], bfr[j], acc[i][j], 0, 0, 0);
  }
}

__device__ __forceinline__ void mainloop(
    const u16* __restrict__ A, const u16* __restrict__ B, int K,
    int kbeg, int kend, int tid, u16* lds, f32x16 (&acc)[2][2]) {
  constexpr int BK = 64;
  constexpr int BUF = 16384;           // u16 per LDS buffer (32 KiB)
  const int lane = tid & 63;
  const int wave = tid >> 6;
  const int wrow = wave >> 1, wcol = wave & 1;

  stage_tile(A, B, K, kbeg, tid, lds); // prologue: tile 0 -> buf 0
  int cur = 0;
  for (int k0 = kbeg; k0 < kend; k0 += BK) {
    if (k0 + BK < kend) {
      stage_tile(A, B, K, k0 + BK, tid, lds + (cur ^ 1) * BUF);
      asm volatile("s_waitcnt vmcnt(8)" ::: "memory");
    } else {
      asm volatile("s_waitcnt vmcnt(0)" ::: "memory");
    }
    __builtin_amdgcn_s_barrier();      // all waves: current buffer complete
    compute_tile(lds + cur * BUF, lane, wrow, wcol, acc);
    __builtin_amdgcn_s_barrier();      // all waves done reading before next
    cur ^= 1;                          // iter overwrites this buffer
  }
}

// 32x32 C/D mapping (m74/m101 verified): col = lane&31,
// row = (reg&3) + 8*(reg>>2) + 4*(lane>>5), reg in [0,16).

// ---- GEMM1+GEMM2 merged: [x; proto](4608 x 1024) @ feat^T, tile 128x128 ----
// 1D grid 576; XCD-supertile decode: XCD k = bid%8 owns a 9x8 tile panel.
// x-rows  -> Acat[row, f]=xf*relu(xf), Acat[row, 2048+f]=1-relu(xf)
// p-rows  -> Bcat[row, f]=th*c-al*(1-pres), Bcat[row, 2048+f]=-be*c
// Epilogue: LDS transpose (stride 136 u16 = 17x16B) -> 128B-coalesced stores.
__global__ __launch_bounds__(256) void gemm12(
    const u16* __restrict__ xb, const u16* __restrict__ pb,
    const u16* __restrict__ fb, u16* __restrict__ Acat, u16* __restrict__ Bcat,
    const float* __restrict__ alpha, const float* __restrict__ beta,
    const float* __restrict__ theta) {
  constexpr int TM = 128, K = 1024, N = 2048;
  constexpr int TSTRIDE = 136;           // u16; 272B rows = 17*16B aligned
  __shared__ u16 lds[32768];             // 64 KiB: 2 mainloop bufs; transpose reuses

  const int tid = threadIdx.x;
  const int lane = tid & 63;
  const int wave = tid >> 6;
  const int wrow = wave >> 1, wcol = wave & 1;

  // XCD-aware supertile decode (bijective: 576 = 8 * 72, panels 9x8)
  const int bid = blockIdx.x;
  const int xcd = bid & 7, slot = bid >> 3;        // xcd 0..7, slot 0..71
  const int xt = (xcd & 3) * 9 + (slot >> 3);      // 0..35
  const int yt = (xcd >> 2) * 8 + (slot & 7);      // 0..15

  const int bm_all = xt * TM;
  const int bn = yt * 128;
  const bool is_x = bm_all < 4096;       // block purely x or proto (4096%128==0)
  const u16* A = is_x ? xb + (size_t)bm_all * K : pb + (size_t)(bm_all - 4096) * K;
  const u16* B = fb + (size_t)bn * K;

  f32x16 acc[2][2] = {};
  mainloop(A, B, K, 0, K, tid, lds, acc);

  float th = 0.f, al = 0.f, be = 0.f;
  if (!is_x) { th = theta[0]; al = alpha[0]; be = beta[0]; }
  u16* dst = is_x ? Acat : Bcat;
  const int rowbase = is_x ? bm_all : bm_all - 4096;
  const int rquad = 4 * (lane >> 5);

  #pragma unroll
  for (int half = 0; half < 2; ++half) {
    __syncthreads();   // protect lds reuse (mainloop end / previous half's reads)
    #pragma unroll
    for (int i = 0; i < 2; ++i) {
      #pragma unroll
      for (int j = 0; j < 2; ++j) {
        const int cl = wcol * 64 + j * 32 + (lane & 31);
        #pragma unroll
        for (int r = 0; r < 16; ++r) {
          const int rl = wrow * 64 + i * 32 + (r & 3) + 8 * (r >> 2) + rquad;
          float v = acc[i][j][r];
          float pres = v > 0.f ? v : 0.f;
          float o;
          if (is_x) o = half == 0 ? v * pres : 1.f - pres;
          else {
            float cc = v * pres;
            o = half == 0 ? th * cc - al * (1.f - pres) : -be * cc;
          }
          lds[rl * TSTRIDE + cl] = f2bf(o);
        }
      }
    }
    __syncthreads();
    #pragma unroll
    for (int v = 0; v < 8; ++v) {
      const int rl = v * 16 + (tid >> 4);
      const int c8 = (tid & 15) * 8;
      u16x8 vec = *(const u16x8*)&lds[rl * TSTRIDE + c8];
      *(u16x8*)&dst[(size_t)(rowbase + rl) * (2 * N) + bn + c8 + half * N] = vec;
    }
  }
}

// ---- GEMM3 split-K: out += Acat @ Bcat^T slice via fp32 atomics ----
// 1D grid 512; XCD-supertile decode: XCD k = bid%8 owns 16x * 4y * 1z
// (z = k/2, xh = k%2). KSPLIT=4. Epilogue: 64 atomicAdd/thread straight to
// out (wave = 2 rows x 32 consecutive floats = 2x128B segments/instr).
// No partials, no reduce kernel (R21). zero_out must precede (stream order).
__global__ __launch_bounds__(256) void gemm3(
    const u16* __restrict__ Acat, const u16* __restrict__ Bcat,
    float* __restrict__ out) {
  constexpr int TM = 128, TN = 128, K = 4096, KSPLIT = 4, N = 512;
  __shared__ u16 lds[32768];             // 64 KiB: 2 mainloop bufs

  const int tid = threadIdx.x;
  const int lane = tid & 63;
  const int wave = tid >> 6;
  const int wrow = wave >> 1, wcol = wave & 1;

  // XCD-aware supertile decode (bijective: 512 = 8 * 64, panels 16x4x1)
  const int bid = blockIdx.x;
  const int xcd = bid & 7, slot = bid >> 3;        // xcd 0..7, slot 0..63
  const int bz = xcd >> 1;                         // 0..3 (K quarter)
  const int bxt = (xcd & 1) * 16 + (slot >> 2);    // 0..31
  const int byt = slot & 3;                        // 0..3

  const int bm = bxt * TM;
  const int bn = byt * TN;
  const int kbeg = bz * (K / KSPLIT);
  const int kend = kbeg + (K / KSPLIT);

  f32x16 acc[2][2] = {};
  mainloop(Acat + (size_t)bm * K, Bcat + (size_t)bn * K, K, kbeg, kend,
           tid, lds, acc);

  // fp32 atomic scatter: row = bm+wrow*64+i*32+(reg&3)+8*(reg>>2)+4*(lane>>5),
  // col = bn+wcol*64+j*32+(lane&31)   (m74/m101 C/D mapping)
  const int gcb = bn + wcol * 64 + (lane & 31);
  const int grb = bm + wrow * 64 + 4 * (lane >> 5);
  #pragma unroll
  for (int i = 0; i < 2; ++i)
    #pragma unroll
    for (int j = 0; j < 2; ++j)
      #pragma unroll
      for (int r = 0; r < 16; ++r) {
        const int row = grb + i * 32 + (r & 3) + 8 * (r >> 2);
        atomicAdd(&out[(size_t)row * N + gcb + j * 32], acc[i][j][r]);
      }
}

extern "C" void kernel_launch(void* const* d_in, const int* in_sizes, int n_in,
                              void* d_out, int out_size, void* d_ws, size_t ws_size,
                              hipStream_t stream) {
  const float* x     = (const float*)d_in[0];
  const float* feat  = (const float*)d_in[1];
  const float* proto = (const float*)d_in[2];
  const float* alpha = (const float*)d_in[3];
  const float* beta  = (const float*)d_in[4];
  const float* theta = (const float*)d_in[5];
  float* out = (float*)d_out;

  constexpr int Bb = 4096, Ii = 1024, Pp = 512, Ff = 2048;

  // ws layout (NO aliasing — R12 defensive change): casts | Acat | Bcat.
  // part region removed (R21: atomic accumulation). ~71 MB of 256 MiB ws.
  char* ws = (char*)d_ws;
  u16* xb   = (u16*)ws;                               // 8.4 MB
  u16* fb   = xb + (size_t)Bb * Ii;                   // 4.2 MB
  u16* pb   = fb + (size_t)Ff * Ii;                   // 1.0 MB
  size_t r0 = 33554432;                               // 32 MiB region0 (casts)
  u16* Acat = (u16*)(ws + r0);                        // 33.6 MB
  u16* Bcat = Acat + (size_t)Bb * 2 * Ff;             // 4.2 MB

  // zero the accumulation target first (independent; ~1.3us)
  zero_out<<<(Bb * Pp / 8) / 256, 256, 0, stream>>>(out);

  const int n1 = Bb * Ii, n2 = Ff * Ii, n3 = Pp * Ii;
  cast3<<<((n1 + n2 + n3) / 8 + 255) / 256, 256, 0, stream>>>(
      x, feat, proto, xb, n1, n2, n3);

  // merged GEMM1+GEMM2: M=4608, N=2048; 1D grid 576 with XCD supertile decode
  gemm12<<<576, 256, 0, stream>>>(xb, pb, fb, Acat, Bcat, alpha, beta, theta);

  // GEMM3: 4096x512, K=4096 split 4 ways; atomic fp32 accumulation into out
  gemm3<<<512, 256, 0, stream>>>(Acat, Bcat, out);
}

// Round 10
// 138.286 us; speedup vs baseline: 1.1375x; 1.1375x over previous
//
#include <hip/hip_runtime.h>
#include <cstdint>

typedef __attribute__((ext_vector_type(8))) short bf16x8;    // 8 bf16 = 4 VGPRs
typedef __attribute__((ext_vector_type(16))) float f32x16;   // 32x32 MFMA C/D
typedef __attribute__((ext_vector_type(4))) float f4;
typedef __attribute__((ext_vector_type(8))) unsigned short u16x8;
typedef unsigned short u16;

// JOURNAL:
// R9: 32x32x16 MFMA beats 16x16x32. R11/R12: ws aliasing abort -> fixed.
// R13 FAILED: 128^2 tile alone: 47.2us gemm12. R14 PARTIAL: 2-phase dbuf +
//      counted vmcnt(8): GEMMs ~41us each, 139.7 total.
// R16 BEST=137.66: + XCD supertile swizzle. ACCOUNTING: kernels ~95us; ~42us =
//      harness 256MiB ws re-poison (fillBuffer) in timed window — fixed cost.
// R17 FAILED (148.2): m97-parity single-buf gemm3 (drain serializes at 8 iters).
// R18 NEUTRAL: 256^2 2-phase gemm3 ~same (halved staging traffic, same time).
// R19/R20 NEUTRAL-WORSE (142.5/148.3): deep ring (BK=32 depth-3 counted vmcnt
//      + setprio). R19's gemm12=59us row = clock-throttled replay artifact.
// R21 FAILED (157.3): fp32 atomicAdd epilogue for gemm3. gemm3 itself only
//      +2us, but ~20us SYSTEMIC cost (dirty-line writeback/flush between
//      dispatches; second fill row in timed window) — R7's atomic lesson
//      repeats. Also: the 2.1-2.5M bank-conflict counts come from mainloop
//      b128 floor behavior (uniform 8 lanes/bank-group), NOT the epilogue —
//      benign vs m98's 1.7e7 reference.
// CONCLUSION R13-R21: six mechanisms tested (residency, tile intensity x2,
//      deep pipeline x2, epilogue restructure); ALL land 41+-5us/GEMM
//      (~470 TF, 19% peak) at these 2048-class shapes — above m102's curve
//      for the m97 structure (320 TF @ N=2048). NOT claiming roofline
//      (rule #10: hipBLASLt-class would do better), but schedule-space is
//      exhausted for this session's one-shot-per-round budget.
// R22 (this round): exact revert to R16 measured best. No new variables.

__device__ __forceinline__ u16 f2bf(float f) {
  uint32_t u = __builtin_bit_cast(uint32_t, f);
  u += 0x7fffu + ((u >> 16) & 1u);          // round-to-nearest-even
  return (u16)(u >> 16);
}

__device__ __forceinline__ float bf2f(u16 h) {
  return __builtin_bit_cast(float, (uint32_t)h << 16);
}

__device__ __forceinline__ void async_cp16(const void* g, void* l) {
  __builtin_amdgcn_global_load_lds(
      (const __attribute__((address_space(1))) uint32_t*)g,
      (__attribute__((address_space(3))) uint32_t*)l, 16, 0, 0);
}

// cast x | features | prototypes -> contiguous bf16 region in ws (8 elem/thread)
__global__ __launch_bounds__(256) void cast3(
    const float* __restrict__ x, const float* __restrict__ f,
    const float* __restrict__ p, u16* __restrict__ dst,
    int n1, int n2, int n3) {
  int i = (blockIdx.x * 256 + threadIdx.x) * 8;
  const float* src;
  int local;
  if (i < n1) { src = x; local = i; }
  else if (i < n1 + n2) { src = f; local = i - n1; }
  else if (i < n1 + n2 + n3) { src = p; local = i - n1 - n2; }
  else return;
  f4 a = *(const f4*)(src + local);
  f4 b = *(const f4*)(src + local + 4);
  u16x8 o;
  o[0] = f2bf(a.x); o[1] = f2bf(a.y); o[2] = f2bf(a.z); o[3] = f2bf(a.w);
  o[4] = f2bf(b.x); o[5] = f2bf(b.y); o[6] = f2bf(b.z); o[7] = f2bf(b.w);
  *(u16x8*)(dst + i) = o;
}

// ---- 2-phase pipelined main loop (TM=128, TN=128, BK=64) ----
// C += A @ B^T with 32x32x16 MFMA. 16B-chunk XOR swizzle.
// Wave grid 2x2: wave covers 64x64 = 2x2 acc tiles of 32x32.
// Double-buffered LDS; next tile's 8 global_load_lds issued BEFORE compute,
// then counted s_waitcnt vmcnt(8) (NOT 0) + raw s_barrier: next-tile loads
// stay in flight across the whole compute phase (T3/T4 minimum recipe).

__device__ __forceinline__ void stage_tile(
    const u16* __restrict__ A, const u16* __restrict__ B, int K,
    int k0, int tid, u16* L) {
  constexpr int TM = 128, TN = 128;
  const int wave = tid >> 6;
  #pragma unroll
  for (int it = 0; it < TM / 32; ++it) {
    int c = it * 256 + tid;            // chunk index = LDS position
    int row = c >> 3, pc = c & 7;
    int gc = pc ^ (row & 7);           // which global 16B chunk lands here
    async_cp16(A + (size_t)row * K + (k0 + gc * 8),
               &L[(it * 256 + wave * 64) * 8]);
  }
  #pragma unroll
  for (int it = 0; it < TN / 32; ++it) {
    int c = it * 256 + tid;
    int row = c >> 3, pc = c & 7;
    int gc = pc ^ (row & 7);
    async_cp16(B + (size_t)row * K + (k0 + gc * 8),
               &L[TM * 64 + (it * 256 + wave * 64) * 8]);
  }
}

__device__ __forceinline__ void compute_tile(
    const u16* L, int lane, int wrow, int wcol, f32x16 (&acc)[2][2]) {
  constexpr int TM = 128;
  #pragma unroll
  for (int s = 0; s < 4; ++s) {        // 4 k-steps of K=16
    const int h = s * 2 + (lane >> 5); // 16B chunk along K this lane needs
    bf16x8 bfr[2], afr[2];
    #pragma unroll
    for (int j = 0; j < 2; ++j) {
      const int rb = wcol * 64 + j * 32 + (lane & 31);
      bfr[j] = *(const bf16x8*)&L[TM * 64 + (rb * 8 + (h ^ (rb & 7))) * 8];
    }
    #pragma unroll
    for (int i = 0; i < 2; ++i) {
      const int ra = wrow * 64 + i * 32 + (lane & 31);
      afr[i] = *(const bf16x8*)&L[(ra * 8 + (h ^ (ra & 7))) * 8];
    }
    #pragma unroll
    for (int i = 0; i < 2; ++i)
      #pragma unroll
      for (int j = 0; j < 2; ++j)
        acc[i][j] = __builtin_amdgcn_mfma_f32_32x32x16_bf16(
            afr[i], bfr[j], acc[i][j], 0, 0, 0);
  }
}

__device__ __forceinline__ void mainloop(
    const u16* __restrict__ A, const u16* __restrict__ B, int K,
    int kbeg, int kend, int tid, u16* lds, f32x16 (&acc)[2][2]) {
  constexpr int BK = 64;
  constexpr int BUF = 16384;           // u16 per LDS buffer (32 KiB)
  const int lane = tid & 63;
  const int wave = tid >> 6;
  const int wrow = wave >> 1, wcol = wave & 1;

  stage_tile(A, B, K, kbeg, tid, lds); // prologue: tile 0 -> buf 0
  int cur = 0;
  for (int k0 = kbeg; k0 < kend; k0 += BK) {
    if (k0 + BK < kend) {
      // issue next tile into the other buffer, then wait ONLY the 8 older
      // loads (current tile); next tile's 8 remain in flight during compute.
      stage_tile(A, B, K, k0 + BK, tid, lds + (cur ^ 1) * BUF);
      asm volatile("s_waitcnt vmcnt(8)" ::: "memory");
    } else {
      asm volatile("s_waitcnt vmcnt(0)" ::: "memory");
    }
    __builtin_amdgcn_s_barrier();      // all waves: current buffer complete
    compute_tile(lds + cur * BUF, lane, wrow, wcol, acc);
    __builtin_amdgcn_s_barrier();      // all waves done reading before next
    cur ^= 1;                          // iter overwrites this buffer
  }
}

// 32x32 C/D mapping (m74/m101 verified): col = lane&31,
// row = (reg&3) + 8*(reg>>2) + 4*(lane>>5), reg in [0,16).

// ---- GEMM1+GEMM2 merged: [x; proto](4608 x 1024) @ feat^T, tile 128x128 ----
// 1D grid 576; XCD-supertile decode: XCD k = bid%8 owns a 9x8 tile panel
// (kx=k%4, ky=k/4): x = kx*9 + slot/8, y = ky*8 + slot%8, slot = bid/8.
// Panel working set = 9 A-tiles (2.25MB) + 8 B-tiles (2MB) ~= 4MB L2.
// x-rows  -> Acat[row, f]=xf*relu(xf), Acat[row, 2048+f]=1-relu(xf)
// p-rows  -> Bcat[row, f]=th*c-al*(1-pres), Bcat[row, 2048+f]=-be*c
// Epilogue: LDS transpose (stride 136 u16 = 17x16B) -> 128B-coalesced stores.
__global__ __launch_bounds__(256) void gemm12(
    const u16* __restrict__ xb, const u16* __restrict__ pb,
    const u16* __restrict__ fb, u16* __restrict__ Acat, u16* __restrict__ Bcat,
    const float* __restrict__ alpha, const float* __restrict__ beta,
    const float* __restrict__ theta) {
  constexpr int TM = 128, K = 1024, N = 2048;
  constexpr int TSTRIDE = 136;           // u16; 272B rows = 17*16B aligned
  __shared__ u16 lds[32768];             // 64 KiB: 2 mainloop bufs; transpose reuses

  const int tid = threadIdx.x;
  const int lane = tid & 63;
  const int wave = tid >> 6;
  const int wrow = wave >> 1, wcol = wave & 1;

  // XCD-aware supertile decode (bijective: 576 = 8 * 72, panels 9x8)
  const int bid = blockIdx.x;
  const int xcd = bid & 7, slot = bid >> 3;        // xcd 0..7, slot 0..71
  const int xt = (xcd & 3) * 9 + (slot >> 3);      // 0..35
  const int yt = (xcd >> 2) * 8 + (slot & 7);      // 0..15

  const int bm_all = xt * TM;
  const int bn = yt * 128;
  const bool is_x = bm_all < 4096;       // block purely x or proto (4096%128==0)
  const u16* A = is_x ? xb + (size_t)bm_all * K : pb + (size_t)(bm_all - 4096) * K;
  const u16* B = fb + (size_t)bn * K;

  f32x16 acc[2][2] = {};
  mainloop(A, B, K, 0, K, tid, lds, acc);

  float th = 0.f, al = 0.f, be = 0.f;
  if (!is_x) { th = theta[0]; al = alpha[0]; be = beta[0]; }
  u16* dst = is_x ? Acat : Bcat;
  const int rowbase = is_x ? bm_all : bm_all - 4096;
  const int rquad = 4 * (lane >> 5);

  #pragma unroll
  for (int half = 0; half < 2; ++half) {
    __syncthreads();   // protect lds reuse (mainloop end / previous half's reads)
    #pragma unroll
    for (int i = 0; i < 2; ++i) {
      #pragma unroll
      for (int j = 0; j < 2; ++j) {
        const int cl = wcol * 64 + j * 32 + (lane & 31);
        #pragma unroll
        for (int r = 0; r < 16; ++r) {
          const int rl = wrow * 64 + i * 32 + (r & 3) + 8 * (r >> 2) + rquad;
          float v = acc[i][j][r];
          float pres = v > 0.f ? v : 0.f;
          float o;
          if (is_x) o = half == 0 ? v * pres : 1.f - pres;
          else {
            float cc = v * pres;
            o = half == 0 ? th * cc - al * (1.f - pres) : -be * cc;
          }
          lds[rl * TSTRIDE + cl] = f2bf(o);
        }
      }
    }
    __syncthreads();
    #pragma unroll
    for (int v = 0; v < 8; ++v) {
      const int rl = v * 16 + (tid >> 4);
      const int c8 = (tid & 15) * 8;
      u16x8 vec = *(const u16x8*)&lds[rl * TSTRIDE + c8];
      *(u16x8*)&dst[(size_t)(rowbase + rl) * (2 * N) + bn + c8 + half * N] = vec;
    }
  }
}

// ---- GEMM3 split-K: part[z] = Acat @ Bcat^T partial (bf16), tile 128x128 ----
// 1D grid 512; XCD-supertile decode: XCD k = bid%8 owns 16x * 4y * 1z
// (z = k/2, xh = k%2): x = xh*16 + slot/4, y = slot%4. Panel = 16 A-tiles
// (4MB) + 4 B-tiles (1MB). Partials bf16 thread-linear, chunk q = i*4+j*2+h.
__global__ __launch_bounds__(256) void gemm3(
    const u16* __restrict__ Acat, const u16* __restrict__ Bcat,
    u16* __restrict__ part) {
  constexpr int TM = 128, TN = 128, K = 4096, KSPLIT = 4;
  __shared__ u16 lds[32768];             // 64 KiB: 2 mainloop bufs

  const int tid = threadIdx.x;

  // XCD-aware supertile decode (bijective: 512 = 8 * 64, panels 16x4x1)
  const int bid = blockIdx.x;
  const int xcd = bid & 7, slot = bid >> 3;        // xcd 0..7, slot 0..63
  const int bz = xcd >> 1;                         // 0..3 (K quarter)
  const int bxt = (xcd & 1) * 16 + (slot >> 2);    // 0..31
  const int byt = slot & 3;                        // 0..3

  const int bm = bxt * TM;
  const int bn = byt * TN;
  const int kbeg = bz * (K / KSPLIT);
  const int kend = kbeg + (K / KSPLIT);

  f32x16 acc[2][2] = {};
  mainloop(Acat + (size_t)bm * K, Bcat + (size_t)bn * K, K, kbeg, kend,
           tid, lds, acc);

  const size_t pbase = ((size_t)bz * 128 + byt * 32 + bxt) * 16384;
  #pragma unroll
  for (int i = 0; i < 2; ++i)
    #pragma unroll
    for (int j = 0; j < 2; ++j)
      #pragma unroll
      for (int h = 0; h < 2; ++h) {
        u16x8 o;
        #pragma unroll
        for (int e = 0; e < 8; ++e) o[e] = f2bf(acc[i][j][h * 8 + e]);
        *(u16x8*)&part[pbase + (size_t)(i * 4 + j * 2 + h) * 2048 + tid * 8] = o;
      }
}

// ---- reduce bf16 partials over z=0..4, scatter fp32 to out ----
// 1024 blocks: one q-chunk per block (tileId = bx>>3, q = bx&7). Mirrors
// gemm3 map: q = i*4+j*2+h; reg = h*8+e; row = bm + wrow*64 + i*32 +
// (reg&3)+8*(reg>>2)+4*(lane>>5); col = bn + wcol*64 + j*32 + (lane&31).
__global__ __launch_bounds__(256) void reduce4(
    const u16* __restrict__ part, float* __restrict__ out) {
  constexpr int N = 512;
  const int tid = threadIdx.x;
  const int lane = tid & 63;
  const int wave = tid >> 6;
  const int wrow = wave >> 1, wcol = wave & 1;
  const int tileId = blockIdx.x >> 3;      // 0..127 = by*32+bx
  const int q = blockIdx.x & 7;
  const int bm = (tileId & 31) * 128;
  const int bn = (tileId >> 5) * 128;

  float v[8] = {};
  #pragma unroll
  for (int z = 0; z < 4; ++z) {
    u16x8 u = *(const u16x8*)&part[((size_t)z * 128 + tileId) * 16384 +
                                   (size_t)q * 2048 + tid * 8];
    #pragma unroll
    for (int e = 0; e < 8; ++e) v[e] += bf2f(u[e]);
  }
  const int i = q >> 2, j = (q >> 1) & 1, h = q & 1;
  const int gc = bn + wcol * 64 + j * 32 + (lane & 31);
  const int grb = bm + wrow * 64 + i * 32 + 4 * (lane >> 5);
  #pragma unroll
  for (int e = 0; e < 8; ++e) {
    const int reg = h * 8 + e;
    out[(size_t)(grb + (reg & 3) + 8 * (reg >> 2)) * N + gc] = v[e];
  }
}

extern "C" void kernel_launch(void* const* d_in, const int* in_sizes, int n_in,
                              void* d_out, int out_size, void* d_ws, size_t ws_size,
                              hipStream_t stream) {
  const float* x     = (const float*)d_in[0];
  const float* feat  = (const float*)d_in[1];
  const float* proto = (const float*)d_in[2];
  const float* alpha = (const float*)d_in[3];
  const float* beta  = (const float*)d_in[4];
  const float* theta = (const float*)d_in[5];
  float* out = (float*)d_out;

  constexpr int Bb = 4096, Ii = 1024, Pp = 512, Ff = 2048;

  // ws layout (NO aliasing — R12 defensive change): casts | Acat | Bcat | part.
  // Total ~88 MB of the 256 MiB workspace.
  char* ws = (char*)d_ws;
  u16* xb   = (u16*)ws;                               // 8.4 MB
  u16* fb   = xb + (size_t)Bb * Ii;                   // 4.2 MB
  u16* pb   = fb + (size_t)Ff * Ii;                   // 1.0 MB
  size_t r0 = 33554432;                               // 32 MiB region0 (casts)
  u16* Acat = (u16*)(ws + r0);                        // 33.6 MB
  u16* Bcat = Acat + (size_t)Bb * 2 * Ff;             // 4.2 MB
  u16* part = Bcat + (size_t)Pp * 2 * Ff;             // 16.8 MB (dedicated)

  const int n1 = Bb * Ii, n2 = Ff * Ii, n3 = Pp * Ii;
  cast3<<<((n1 + n2 + n3) / 8 + 255) / 256, 256, 0, stream>>>(
      x, feat, proto, xb, n1, n2, n3);

  // merged GEMM1+GEMM2: M=4608, N=2048; 1D grid 576 with XCD supertile decode
  gemm12<<<576, 256, 0, stream>>>(xb, pb, fb, Acat, Bcat, alpha, beta, theta);

  // GEMM3: 4096x512, K=4096 split 4 ways; 1D grid 512 with XCD supertile decode
  gemm3<<<512, 256, 0, stream>>>(Acat, Bcat, part);

  // reduce z=0..4 -> out (8 blocks per tile, one q-chunk each)
  reduce4<<<1024, 256, 0, stream>>>(part, out);
}

// Round 11
// 134.942 us; speedup vs baseline: 1.1657x; 1.0248x over previous
//
#include <hip/hip_runtime.h>
#include <cstdint>

typedef __attribute__((ext_vector_type(8))) short bf16x8;    // 8 bf16 = 4 VGPRs
typedef __attribute__((ext_vector_type(16))) float f32x16;   // 32x32 MFMA C/D
typedef __attribute__((ext_vector_type(4))) float f4;
typedef __attribute__((ext_vector_type(8))) unsigned short u16x8;
typedef unsigned short u16;

// JOURNAL:
// R9: 32x32x16 MFMA beats 16x16x32. R11/R12: ws aliasing abort -> fixed.
// R13 FAILED: 128^2 tile, no pipeline: 47.2us gemm12.
// R14 PARTIAL: 2-phase dbuf + counted vmcnt(8): GEMMs ~41us each, 139.7.
// R16 BEST=137.7: + XCD supertile swizzle. ~42us of dur = harness 256MiB ws
//      re-poison (fixed); kernels sum ~95us.
// R17-R21 FAILED/NEUTRAL: m97-single-buf (148), 256^2 2ph (neutral), deep ring
//      BK=32 x2 (142/148 — BK=32's 4-chunk rows use half the LDS bank-groups
//      => 2x read cycles, masking any prefetch gain), atomicAdd epilogue
//      (157: ~20us systemic writeback cost — R7's lesson).
// R22: exact revert to R16 => 138.3 ✓ (noise band). Resource math per CU
//      (gemm12): MFMA 3.8us, LDS 15us, staging ~10us vs 41us actual —
//      pure exposed latency; nothing saturated.
// R23 (this round): SINGLE VARIABLE: 4 -> 8 waves/block (256->512 thr) at the
//      IDENTICAL R16 structure (same tile/BK/swizzle/2-phase skeleton).
//      Per-block totals unchanged; only wave decomposition finer: per-wave
//      32x128 out = acc[2] (~-96 VGPR), 4 loads/thread -> vmcnt(4).
//      16 waves/CU (2 blk x 8) vs 8 — m97 ran 12-16 (m114 co-issue needs
//      wave diversity). Predict: win => GEMMs ~30-34, total ~122-128,
//      MfmaUtil ~21%. Null (138+-2) => latency wall fundamental; hold R16.

__device__ __forceinline__ u16 f2bf(float f) {
  uint32_t u = __builtin_bit_cast(uint32_t, f);
  u += 0x7fffu + ((u >> 16) & 1u);          // round-to-nearest-even
  return (u16)(u >> 16);
}

__device__ __forceinline__ float bf2f(u16 h) {
  return __builtin_bit_cast(float, (uint32_t)h << 16);
}

__device__ __forceinline__ void async_cp16(const void* g, void* l) {
  __builtin_amdgcn_global_load_lds(
      (const __attribute__((address_space(1))) uint32_t*)g,
      (__attribute__((address_space(3))) uint32_t*)l, 16, 0, 0);
}

// cast x | features | prototypes -> contiguous bf16 region in ws (8 elem/thread)
__global__ __launch_bounds__(256) void cast3(
    const float* __restrict__ x, const float* __restrict__ f,
    const float* __restrict__ p, u16* __restrict__ dst,
    int n1, int n2, int n3) {
  int i = (blockIdx.x * 256 + threadIdx.x) * 8;
  const float* src;
  int local;
  if (i < n1) { src = x; local = i; }
  else if (i < n1 + n2) { src = f; local = i - n1; }
  else if (i < n1 + n2 + n3) { src = p; local = i - n1 - n2; }
  else return;
  f4 a = *(const f4*)(src + local);
  f4 b = *(const f4*)(src + local + 4);
  u16x8 o;
  o[0] = f2bf(a.x); o[1] = f2bf(a.y); o[2] = f2bf(a.z); o[3] = f2bf(a.w);
  o[4] = f2bf(b.x); o[5] = f2bf(b.y); o[6] = f2bf(b.z); o[7] = f2bf(b.w);
  *(u16x8*)(dst + i) = o;
}

// ---- 2-phase pipelined main loop (TM=128, TN=128, BK=64), 512 threads ----
// C += A @ B^T with 32x32x16 MFMA. Same 16B-chunk XOR swizzle as R16
// (8 chunks/row: balanced over all 8 LDS bank-groups — do NOT shrink).
// 8 waves in 4x2 grid: wave covers 32 rows x 128 cols = 1x2 acc tiles.
// Double-buffered LDS; next tile's 4 global_load_lds issued BEFORE compute,
// then counted s_waitcnt vmcnt(4) + raw s_barrier (T3/T4 minimum recipe).

__device__ __forceinline__ void stage_tile512(
    const u16* __restrict__ A, const u16* __restrict__ B, int K,
    int k0, int tid, u16* L) {
  const int wave = tid >> 6;
  #pragma unroll
  for (int it = 0; it < 2; ++it) {     // A: 128 rows x 8 chunks = 1024
    int c = it * 512 + tid;            // chunk index = LDS position
    int row = c >> 3, pc = c & 7;
    int gc = pc ^ (row & 7);           // which global 16B chunk lands here
    async_cp16(A + (size_t)row * K + (k0 + gc * 8),
               &L[(it * 512 + wave * 64) * 8]);
  }
  #pragma unroll
  for (int it = 0; it < 2; ++it) {     // B: 128 rows x 8 chunks
    int c = it * 512 + tid;
    int row = c >> 3, pc = c & 7;
    int gc = pc ^ (row & 7);
    async_cp16(B + (size_t)row * K + (k0 + gc * 8),
               &L[8192 + (it * 512 + wave * 64) * 8]);
  }
}

__device__ __forceinline__ void compute_tile512(
    const u16* L, int lane, int wrow, int wcol, f32x16 (&acc)[2]) {
  #pragma unroll
  for (int s = 0; s < 4; ++s) {        // 4 k-steps of K=16
    const int h = s * 2 + (lane >> 5); // 16B chunk along K this lane needs
    const int ra = wrow * 32 + (lane & 31);
    bf16x8 afr = *(const bf16x8*)&L[(ra * 8 + (h ^ (ra & 7))) * 8];
    #pragma unroll
    for (int j = 0; j < 2; ++j) {
      const int rb = wcol * 64 + j * 32 + (lane & 31);
      bf16x8 bfr = *(const bf16x8*)&L[8192 + (rb * 8 + (h ^ (rb & 7))) * 8];
      acc[j] = __builtin_amdgcn_mfma_f32_32x32x16_bf16(afr, bfr, acc[j], 0, 0, 0);
    }
  }
}

__device__ __forceinline__ void mainloop512(
    const u16* __restrict__ A, const u16* __restrict__ B, int K,
    int kbeg, int kend, int tid, u16* lds, f32x16 (&acc)[2]) {
  constexpr int BK = 64;
  constexpr int BUF = 16384;           // u16 per LDS buffer (32 KiB)
  const int lane = tid & 63;
  const int wave = tid >> 6;
  const int wrow = wave >> 1, wcol = wave & 1;

  stage_tile512(A, B, K, kbeg, tid, lds); // prologue: tile 0 -> buf 0
  int cur = 0;
  for (int k0 = kbeg; k0 < kend; k0 += BK) {
    if (k0 + BK < kend) {
      // issue next tile (4 loads/thread), then wait ONLY the 4 older loads.
      stage_tile512(A, B, K, k0 + BK, tid, lds + (cur ^ 1) * BUF);
      asm volatile("s_waitcnt vmcnt(4)" ::: "memory");
    } else {
      asm volatile("s_waitcnt vmcnt(0)" ::: "memory");
    }
    __builtin_amdgcn_s_barrier();      // all waves: current buffer complete
    compute_tile512(lds + cur * BUF, lane, wrow, wcol, acc);
    __builtin_amdgcn_s_barrier();      // all waves done reading before next
    cur ^= 1;                          // iter overwrites this buffer
  }
}

// 32x32 C/D mapping (m74/m101 verified): col = lane&31,
// row = (reg&3) + 8*(reg>>2) + 4*(lane>>5), reg in [0,16).

// ---- GEMM1+GEMM2 merged: [x; proto](4608 x 1024) @ feat^T, tile 128x128 ----
// 1D grid 576, 512 threads; XCD-supertile decode (9x8 panel per XCD).
// x-rows  -> Acat[row, f]=xf*relu(xf), Acat[row, 2048+f]=1-relu(xf)
// p-rows  -> Bcat[row, f]=th*c-al*(1-pres), Bcat[row, 2048+f]=-be*c
// Epilogue: LDS transpose (stride 136 u16) -> 128B-coalesced u16x8 stores.
__global__ __launch_bounds__(512) void gemm12(
    const u16* __restrict__ xb, const u16* __restrict__ pb,
    const u16* __restrict__ fb, u16* __restrict__ Acat, u16* __restrict__ Bcat,
    const float* __restrict__ alpha, const float* __restrict__ beta,
    const float* __restrict__ theta) {
  constexpr int TM = 128, K = 1024, N = 2048;
  constexpr int TSTRIDE = 136;           // u16; 272B rows = 17*16B aligned
  __shared__ u16 lds[32768];             // 64 KiB: 2 mainloop bufs; transpose reuses

  const int tid = threadIdx.x;
  const int lane = tid & 63;
  const int wave = tid >> 6;
  const int wrow = wave >> 1, wcol = wave & 1;   // 4x2 wave grid

  // XCD-aware supertile decode (bijective: 576 = 8 * 72, panels 9x8)
  const int bid = blockIdx.x;
  const int xcd = bid & 7, slot = bid >> 3;        // xcd 0..7, slot 0..71
  const int xt = (xcd & 3) * 9 + (slot >> 3);      // 0..35
  const int yt = (xcd >> 2) * 8 + (slot & 7);      // 0..15

  const int bm_all = xt * TM;
  const int bn = yt * 128;
  const bool is_x = bm_all < 4096;       // block purely x or proto (4096%128==0)
  const u16* A = is_x ? xb + (size_t)bm_all * K : pb + (size_t)(bm_all - 4096) * K;
  const u16* B = fb + (size_t)bn * K;

  f32x16 acc[2] = {};
  mainloop512(A, B, K, 0, K, tid, lds, acc);

  float th = 0.f, al = 0.f, be = 0.f;
  if (!is_x) { th = theta[0]; al = alpha[0]; be = beta[0]; }
  u16* dst = is_x ? Acat : Bcat;
  const int rowbase = is_x ? bm_all : bm_all - 4096;
  const int rquad = 4 * (lane >> 5);

  #pragma unroll
  for (int half = 0; half < 2; ++half) {
    __syncthreads();   // protect lds reuse (mainloop end / previous half's reads)
    #pragma unroll
    for (int j = 0; j < 2; ++j) {
      const int cl = wcol * 64 + j * 32 + (lane & 31);
      #pragma unroll
      for (int r = 0; r < 16; ++r) {
        const int rl = wrow * 32 + (r & 3) + 8 * (r >> 2) + rquad;
        float v = acc[j][r];
        float pres = v > 0.f ? v : 0.f;
        float o;
        if (is_x) o = half == 0 ? v * pres : 1.f - pres;
        else {
          float cc = v * pres;
          o = half == 0 ? th * cc - al * (1.f - pres) : -be * cc;
        }
        lds[rl * TSTRIDE + cl] = f2bf(o);
      }
    }
    __syncthreads();
    #pragma unroll
    for (int v = 0; v < 4; ++v) {
      const int rl = v * 32 + (tid >> 4);
      const int c8 = (tid & 15) * 8;
      u16x8 vec = *(const u16x8*)&lds[rl * TSTRIDE + c8];
      *(u16x8*)&dst[(size_t)(rowbase + rl) * (2 * N) + bn + c8 + half * N] = vec;
    }
  }
}

// ---- GEMM3 split-K: part[z] = Acat @ Bcat^T partial (bf16), tile 128x128 ----
// 1D grid 512, 512 threads; XCD-supertile decode: XCD k = bid%8 owns
// 16x * 4y * 1z (z = k/2, xh = k%2). KSPLIT=4. Partials bf16 thread-linear:
// tile = 16384 u16; chunk q = j*2 + h (0..3), 4096 u16 each.
__global__ __launch_bounds__(512) void gemm3(
    const u16* __restrict__ Acat, const u16* __restrict__ Bcat,
    u16* __restrict__ part) {
  constexpr int TM = 128, TN = 128, K = 4096, KSPLIT = 4;
  __shared__ u16 lds[32768];             // 64 KiB: 2 mainloop bufs

  const int tid = threadIdx.x;

  // XCD-aware supertile decode (bijective: 512 = 8 * 64, panels 16x4x1)
  const int bid = blockIdx.x;
  const int xcd = bid & 7, slot = bid >> 3;        // xcd 0..7, slot 0..63
  const int bz = xcd >> 1;                         // 0..3 (K quarter)
  const int bxt = (xcd & 1) * 16 + (slot >> 2);    // 0..31
  const int byt = slot & 3;                        // 0..3

  const int bm = bxt * TM;
  const int bn = byt * TN;
  const int kbeg = bz * (K / KSPLIT);
  const int kend = kbeg + (K / KSPLIT);

  f32x16 acc[2] = {};
  mainloop512(Acat + (size_t)bm * K, Bcat + (size_t)bn * K, K, kbeg, kend,
              tid, lds, acc);

  const size_t pbase = ((size_t)bz * 128 + byt * 32 + bxt) * 16384;
  #pragma unroll
  for (int j = 0; j < 2; ++j)
    #pragma unroll
    for (int h = 0; h < 2; ++h) {
      u16x8 o;
      #pragma unroll
      for (int e = 0; e < 8; ++e) o[e] = f2bf(acc[j][h * 8 + e]);
      *(u16x8*)&part[pbase + (size_t)(j * 2 + h) * 4096 + tid * 8] = o;
    }
}

// ---- reduce bf16 partials over z=0..4, scatter fp32 to out ----
// 512 blocks x 512 thr: one q-chunk per block (tileId = bid>>2, q = bid&3).
// Mirrors gemm3 map: q = j*2+h; reg = h*8+e; 4x2 wave grid:
// row = bm + (wave>>1)*32 + (reg&3)+8*(reg>>2)+4*(lane>>5);
// col = bn + (wave&1)*64 + j*32 + (lane&31).
__global__ __launch_bounds__(512) void reduce4(
    const u16* __restrict__ part, float* __restrict__ out) {
  constexpr int N = 512;
  const int tid = threadIdx.x;
  const int lane = tid & 63;
  const int wave = tid >> 6;
  const int wrow = wave >> 1, wcol = wave & 1;
  const int tileId = blockIdx.x >> 2;      // 0..127 = byt*32+bxt
  const int q = blockIdx.x & 3;
  const int bm = (tileId & 31) * 128;
  const int bn = (tileId >> 5) * 128;

  float v[8] = {};
  #pragma unroll
  for (int z = 0; z < 4; ++z) {
    u16x8 u = *(const u16x8*)&part[((size_t)z * 128 + tileId) * 16384 +
                                   (size_t)q * 4096 + tid * 8];
    #pragma unroll
    for (int e = 0; e < 8; ++e) v[e] += bf2f(u[e]);
  }
  const int j = q >> 1, h = q & 1;
  const int gc = bn + wcol * 64 + j * 32 + (lane & 31);
  const int grb = bm + wrow * 32 + 4 * (lane >> 5);
  #pragma unroll
  for (int e = 0; e < 8; ++e) {
    const int reg = h * 8 + e;
    out[(size_t)(grb + (reg & 3) + 8 * (reg >> 2)) * N + gc] = v[e];
  }
}

extern "C" void kernel_launch(void* const* d_in, const int* in_sizes, int n_in,
                              void* d_out, int out_size, void* d_ws, size_t ws_size,
                              hipStream_t stream) {
  const float* x     = (const float*)d_in[0];
  const float* feat  = (const float*)d_in[1];
  const float* proto = (const float*)d_in[2];
  const float* alpha = (const float*)d_in[3];
  const float* beta  = (const float*)d_in[4];
  const float* theta = (const float*)d_in[5];
  float* out = (float*)d_out;

  constexpr int Bb = 4096, Ii = 1024, Pp = 512, Ff = 2048;

  // ws layout (NO aliasing — R12 defensive change): casts | Acat | Bcat | part.
  // Total ~88 MB of the 256 MiB workspace.
  char* ws = (char*)d_ws;
  u16* xb   = (u16*)ws;                               // 8.4 MB
  u16* fb   = xb + (size_t)Bb * Ii;                   // 4.2 MB
  u16* pb   = fb + (size_t)Ff * Ii;                   // 1.0 MB
  size_t r0 = 33554432;                               // 32 MiB region0 (casts)
  u16* Acat = (u16*)(ws + r0);                        // 33.6 MB
  u16* Bcat = Acat + (size_t)Bb * 2 * Ff;             // 4.2 MB
  u16* part = Bcat + (size_t)Pp * 2 * Ff;             // 16.8 MB (dedicated)

  const int n1 = Bb * Ii, n2 = Ff * Ii, n3 = Pp * Ii;
  cast3<<<((n1 + n2 + n3) / 8 + 255) / 256, 256, 0, stream>>>(
      x, feat, proto, xb, n1, n2, n3);

  // merged GEMM1+GEMM2: M=4608, N=2048; 1D grid 576 x 512 threads
  gemm12<<<576, 512, 0, stream>>>(xb, pb, fb, Acat, Bcat, alpha, beta, theta);

  // GEMM3: 4096x512, K=4096 split 4 ways; 1D grid 512 x 512 threads
  gemm3<<<512, 512, 0, stream>>>(Acat, Bcat, part);

  // reduce z=0..4 -> out (4 q-chunks per tile, one per block)
  reduce4<<<512, 512, 0, stream>>>(part, out);
}

// Round 14
// 134.143 us; speedup vs baseline: 1.1726x; 1.0060x over previous
//
#include <hip/hip_runtime.h>
#include <cstdint>

typedef __attribute__((ext_vector_type(8))) short bf16x8;    // 8 bf16 = 4 VGPRs
typedef __attribute__((ext_vector_type(16))) float f32x16;   // 32x32 MFMA C/D
typedef __attribute__((ext_vector_type(4))) float f4;
typedef __attribute__((ext_vector_type(8))) unsigned short u16x8;
typedef unsigned short u16;

// JOURNAL:
// R9: 32x32x16 MFMA. R11/R12: ws aliasing abort -> fixed.
// R13 FAILED: TN 64->128 without pipeline: 47.2us (residency 2.25 blk/CU).
// R14: 2-phase dbuf + counted vmcnt: GEMMs ~41us. R16: +XCD swz = 137.7.
// R17-R21: single-buf/256^2-2ph/deep-ring x2/atomic epilogue — all
//      neutral-to-worse. ~42us of dur = harness ws re-poison (fixed cost).
// R22: revert verified 138.3. Exposed-latency wall: MFMA 3.8us, LDS 15us,
//      staging ~10us per CU vs 41us actual.
// R23 WIN=134.9 (BEST): 4->8 waves/block (512 thr) at identical structure.
//      16 waves/CU vs 8 — wave-level hiding (m114) is the responsive lever.
// R24 FAILED CORRECTNESS: TN->64 / 24 waves/CU variant; unlocalized after
//      full audit. Direction abandoned under one-shot budget.
// R25: resubmit of R23 — INFRA FAIL (container failed twice; same class as
//      R15, no pytest/correctness signal; source byte-identical to the
//      kernel that passed at 134.9).
// R26 (this round): resubmit unchanged again (R15->R16 precedent).

__device__ __forceinline__ u16 f2bf(float f) {
  uint32_t u = __builtin_bit_cast(uint32_t, f);
  u += 0x7fffu + ((u >> 16) & 1u);          // round-to-nearest-even
  return (u16)(u >> 16);
}

__device__ __forceinline__ float bf2f(u16 h) {
  return __builtin_bit_cast(float, (uint32_t)h << 16);
}

__device__ __forceinline__ void async_cp16(const void* g, void* l) {
  __builtin_amdgcn_global_load_lds(
      (const __attribute__((address_space(1))) uint32_t*)g,
      (__attribute__((address_space(3))) uint32_t*)l, 16, 0, 0);
}

// cast x | features | prototypes -> contiguous bf16 region in ws (8 elem/thread)
__global__ __launch_bounds__(256) void cast3(
    const float* __restrict__ x, const float* __restrict__ f,
    const float* __restrict__ p, u16* __restrict__ dst,
    int n1, int n2, int n3) {
  int i = (blockIdx.x * 256 + threadIdx.x) * 8;
  const float* src;
  int local;
  if (i < n1) { src = x; local = i; }
  else if (i < n1 + n2) { src = f; local = i - n1; }
  else if (i < n1 + n2 + n3) { src = p; local = i - n1 - n2; }
  else return;
  f4 a = *(const f4*)(src + local);
  f4 b = *(const f4*)(src + local + 4);
  u16x8 o;
  o[0] = f2bf(a.x); o[1] = f2bf(a.y); o[2] = f2bf(a.z); o[3] = f2bf(a.w);
  o[4] = f2bf(b.x); o[5] = f2bf(b.y); o[6] = f2bf(b.z); o[7] = f2bf(b.w);
  *(u16x8*)(dst + i) = o;
}

// ---- 2-phase pipelined main loop (TM=128, TN=128, BK=64), 512 threads ----
// C += A @ B^T with 32x32x16 MFMA. Same 16B-chunk XOR swizzle as R16
// (8 chunks/row: balanced over all 8 LDS bank-groups — do NOT shrink).
// 8 waves in 4x2 grid: wave covers 32 rows x 128 cols = 1x2 acc tiles.
// Double-buffered LDS; next tile's 4 global_load_lds issued BEFORE compute,
// then counted s_waitcnt vmcnt(4) + raw s_barrier (T3/T4 minimum recipe).

__device__ __forceinline__ void stage_tile512(
    const u16* __restrict__ A, const u16* __restrict__ B, int K,
    int k0, int tid, u16* L) {
  const int wave = tid >> 6;
  #pragma unroll
  for (int it = 0; it < 2; ++it) {     // A: 128 rows x 8 chunks = 1024
    int c = it * 512 + tid;            // chunk index = LDS position
    int row = c >> 3, pc = c & 7;
    int gc = pc ^ (row & 7);           // which global 16B chunk lands here
    async_cp16(A + (size_t)row * K + (k0 + gc * 8),
               &L[(it * 512 + wave * 64) * 8]);
  }
  #pragma unroll
  for (int it = 0; it < 2; ++it) {     // B: 128 rows x 8 chunks
    int c = it * 512 + tid;
    int row = c >> 3, pc = c & 7;
    int gc = pc ^ (row & 7);
    async_cp16(B + (size_t)row * K + (k0 + gc * 8),
               &L[8192 + (it * 512 + wave * 64) * 8]);
  }
}

__device__ __forceinline__ void compute_tile512(
    const u16* L, int lane, int wrow, int wcol, f32x16 (&acc)[2]) {
  #pragma unroll
  for (int s = 0; s < 4; ++s) {        // 4 k-steps of K=16
    const int h = s * 2 + (lane >> 5); // 16B chunk along K this lane needs
    const int ra = wrow * 32 + (lane & 31);
    bf16x8 afr = *(const bf16x8*)&L[(ra * 8 + (h ^ (ra & 7))) * 8];
    #pragma unroll
    for (int j = 0; j < 2; ++j) {
      const int rb = wcol * 64 + j * 32 + (lane & 31);
      bf16x8 bfr = *(const bf16x8*)&L[8192 + (rb * 8 + (h ^ (rb & 7))) * 8];
      acc[j] = __builtin_amdgcn_mfma_f32_32x32x16_bf16(afr, bfr, acc[j], 0, 0, 0);
    }
  }
}

__device__ __forceinline__ void mainloop512(
    const u16* __restrict__ A, const u16* __restrict__ B, int K,
    int kbeg, int kend, int tid, u16* lds, f32x16 (&acc)[2]) {
  constexpr int BK = 64;
  constexpr int BUF = 16384;           // u16 per LDS buffer (32 KiB)
  const int lane = tid & 63;
  const int wave = tid >> 6;
  const int wrow = wave >> 1, wcol = wave & 1;

  stage_tile512(A, B, K, kbeg, tid, lds); // prologue: tile 0 -> buf 0
  int cur = 0;
  for (int k0 = kbeg; k0 < kend; k0 += BK) {
    if (k0 + BK < kend) {
      // issue next tile (4 loads/thread), then wait ONLY the 4 older loads.
      stage_tile512(A, B, K, k0 + BK, tid, lds + (cur ^ 1) * BUF);
      asm volatile("s_waitcnt vmcnt(4)" ::: "memory");
    } else {
      asm volatile("s_waitcnt vmcnt(0)" ::: "memory");
    }
    __builtin_amdgcn_s_barrier();      // all waves: current buffer complete
    compute_tile512(lds + cur * BUF, lane, wrow, wcol, acc);
    __builtin_amdgcn_s_barrier();      // all waves done reading before next
    cur ^= 1;                          // iter overwrites this buffer
  }
}

// 32x32 C/D mapping (m74/m101 verified): col = lane&31,
// row = (reg&3) + 8*(reg>>2) + 4*(lane>>5), reg in [0,16).

// ---- GEMM1+GEMM2 merged: [x; proto](4608 x 1024) @ feat^T, tile 128x128 ----
// 1D grid 576, 512 threads; XCD-supertile decode (9x8 panel per XCD).
// x-rows  -> Acat[row, f]=xf*relu(xf), Acat[row, 2048+f]=1-relu(xf)
// p-rows  -> Bcat[row, f]=th*c-al*(1-pres), Bcat[row, 2048+f]=-be*c
// Epilogue: LDS transpose (stride 136 u16) -> 128B-coalesced u16x8 stores.
__global__ __launch_bounds__(512) void gemm12(
    const u16* __restrict__ xb, const u16* __restrict__ pb,
    const u16* __restrict__ fb, u16* __restrict__ Acat, u16* __restrict__ Bcat,
    const float* __restrict__ alpha, const float* __restrict__ beta,
    const float* __restrict__ theta) {
  constexpr int TM = 128, K = 1024, N = 2048;
  constexpr int TSTRIDE = 136;           // u16; 272B rows = 17*16B aligned
  __shared__ u16 lds[32768];             // 64 KiB: 2 mainloop bufs; transpose reuses

  const int tid = threadIdx.x;
  const int lane = tid & 63;
  const int wave = tid >> 6;
  const int wrow = wave >> 1, wcol = wave & 1;   // 4x2 wave grid

  // XCD-aware supertile decode (bijective: 576 = 8 * 72, panels 9x8)
  const int bid = blockIdx.x;
  const int xcd = bid & 7, slot = bid >> 3;        // xcd 0..7, slot 0..71
  const int xt = (xcd & 3) * 9 + (slot >> 3);      // 0..35
  const int yt = (xcd >> 2) * 8 + (slot & 7);      // 0..15

  const int bm_all = xt * TM;
  const int bn = yt * 128;
  const bool is_x = bm_all < 4096;       // block purely x or proto (4096%128==0)
  const u16* A = is_x ? xb + (size_t)bm_all * K : pb + (size_t)(bm_all - 4096) * K;
  const u16* B = fb + (size_t)bn * K;

  f32x16 acc[2] = {};
  mainloop512(A, B, K, 0, K, tid, lds, acc);

  float th = 0.f, al = 0.f, be = 0.f;
  if (!is_x) { th = theta[0]; al = alpha[0]; be = beta[0]; }
  u16* dst = is_x ? Acat : Bcat;
  const int rowbase = is_x ? bm_all : bm_all - 4096;
  const int rquad = 4 * (lane >> 5);

  #pragma unroll
  for (int half = 0; half < 2; ++half) {
    __syncthreads();   // protect lds reuse (mainloop end / previous half's reads)
    #pragma unroll
    for (int j = 0; j < 2; ++j) {
      const int cl = wcol * 64 + j * 32 + (lane & 31);
      #pragma unroll
      for (int r = 0; r < 16; ++r) {
        const int rl = wrow * 32 + (r & 3) + 8 * (r >> 2) + rquad;
        float v = acc[j][r];
        float pres = v > 0.f ? v : 0.f;
        float o;
        if (is_x) o = half == 0 ? v * pres : 1.f - pres;
        else {
          float cc = v * pres;
          o = half == 0 ? th * cc - al * (1.f - pres) : -be * cc;
        }
        lds[rl * TSTRIDE + cl] = f2bf(o);
      }
    }
    __syncthreads();
    #pragma unroll
    for (int v = 0; v < 4; ++v) {
      const int rl = v * 32 + (tid >> 4);
      const int c8 = (tid & 15) * 8;
      u16x8 vec = *(const u16x8*)&lds[rl * TSTRIDE + c8];
      *(u16x8*)&dst[(size_t)(rowbase + rl) * (2 * N) + bn + c8 + half * N] = vec;
    }
  }
}

// ---- GEMM3 split-K: part[z] = Acat @ Bcat^T partial (bf16), tile 128x128 ----
// 1D grid 512, 512 threads; XCD-supertile decode: XCD k = bid%8 owns
// 16x * 4y * 1z (z = k/2, xh = k%2). KSPLIT=4. Partials bf16 thread-linear:
// tile = 16384 u16; chunk q = j*2 + h (0..3), 4096 u16 each.
__global__ __launch_bounds__(512) void gemm3(
    const u16* __restrict__ Acat, const u16* __restrict__ Bcat,
    u16* __restrict__ part) {
  constexpr int TM = 128, TN = 128, K = 4096, KSPLIT = 4;
  __shared__ u16 lds[32768];             // 64 KiB: 2 mainloop bufs

  const int tid = threadIdx.x;

  // XCD-aware supertile decode (bijective: 512 = 8 * 64, panels 16x4x1)
  const int bid = blockIdx.x;
  const int xcd = bid & 7, slot = bid >> 3;        // xcd 0..7, slot 0..63
  const int bz = xcd >> 1;                         // 0..3 (K quarter)
  const int bxt = (xcd & 1) * 16 + (slot >> 2);    // 0..31
  const int byt = slot & 3;                        // 0..3

  const int bm = bxt * TM;
  const int bn = byt * TN;
  const int kbeg = bz * (K / KSPLIT);
  const int kend = kbeg + (K / KSPLIT);

  f32x16 acc[2] = {};
  mainloop512(Acat + (size_t)bm * K, Bcat + (size_t)bn * K, K, kbeg, kend,
              tid, lds, acc);

  const size_t pbase = ((size_t)bz * 128 + byt * 32 + bxt) * 16384;
  #pragma unroll
  for (int j = 0; j < 2; ++j)
    #pragma unroll
    for (int h = 0; h < 2; ++h) {
      u16x8 o;
      #pragma unroll
      for (int e = 0; e < 8; ++e) o[e] = f2bf(acc[j][h * 8 + e]);
      *(u16x8*)&part[pbase + (size_t)(j * 2 + h) * 4096 + tid * 8] = o;
    }
}

// ---- reduce bf16 partials over z=0..4, scatter fp32 to out ----
// 512 blocks x 512 thr: one q-chunk per block (tileId = bid>>2, q = bid&3).
// Mirrors gemm3 map: q = j*2+h; reg = h*8+e; 4x2 wave grid:
// row = bm + (wave>>1)*32 + (reg&3)+8*(reg>>2)+4*(lane>>5);
// col = bn + (wave&1)*64 + j*32 + (lane&31).
__global__ __launch_bounds__(512) void reduce4(
    const u16* __restrict__ part, float* __restrict__ out) {
  constexpr int N = 512;
  const int tid = threadIdx.x;
  const int lane = tid & 63;
  const int wave = tid >> 6;
  const int wrow = wave >> 1, wcol = wave & 1;
  const int tileId = blockIdx.x >> 2;      // 0..127 = byt*32+bxt
  const int q = blockIdx.x & 3;
  const int bm = (tileId & 31) * 128;
  const int bn = (tileId >> 5) * 128;

  float v[8] = {};
  #pragma unroll
  for (int z = 0; z < 4; ++z) {
    u16x8 u = *(const u16x8*)&part[((size_t)z * 128 + tileId) * 16384 +
                                   (size_t)q * 4096 + tid * 8];
    #pragma unroll
    for (int e = 0; e < 8; ++e) v[e] += bf2f(u[e]);
  }
  const int j = q >> 1, h = q & 1;
  const int gc = bn + wcol * 64 + j * 32 + (lane & 31);
  const int grb = bm + wrow * 32 + 4 * (lane >> 5);
  #pragma unroll
  for (int e = 0; e < 8; ++e) {
    const int reg = h * 8 + e;
    out[(size_t)(grb + (reg & 3) + 8 * (reg >> 2)) * N + gc] = v[e];
  }
}

extern "C" void kernel_launch(void* const* d_in, const int* in_sizes, int n_in,
                              void* d_out, int out_size, void* d_ws, size_t ws_size,
                              hipStream_t stream) {
  const float* x     = (const float*)d_in[0];
  const float* feat  = (const float*)d_in[1];
  const float* proto = (const float*)d_in[2];
  const float* alpha = (const float*)d_in[3];
  const float* beta  = (const float*)d_in[4];
  const float* theta = (const float*)d_in[5];
  float* out = (float*)d_out;

  constexpr int Bb = 4096, Ii = 1024, Pp = 512, Ff = 2048;

  // ws layout (NO aliasing — R12 defensive change): casts | Acat | Bcat | part.
  // Total ~88 MB of the 256 MiB workspace.
  char* ws = (char*)d_ws;
  u16* xb   = (u16*)ws;                               // 8.4 MB
  u16* fb   = xb + (size_t)Bb * Ii;                   // 4.2 MB
  u16* pb   = fb + (size_t)Ff * Ii;                   // 1.0 MB
  size_t r0 = 33554432;                               // 32 MiB region0 (casts)
  u16* Acat = (u16*)(ws + r0);                        // 33.6 MB
  u16* Bcat = Acat + (size_t)Bb * 2 * Ff;             // 4.2 MB
  u16* part = Bcat + (size_t)Pp * 2 * Ff;             // 16.8 MB (dedicated)

  const int n1 = Bb * Ii, n2 = Ff * Ii, n3 = Pp * Ii;
  cast3<<<((n1 + n2 + n3) / 8 + 255) / 256, 256, 0, stream>>>(
      x, feat, proto, xb, n1, n2, n3);

  // merged GEMM1+GEMM2: M=4608, N=2048; 1D grid 576 x 512 threads
  gemm12<<<576, 512, 0, stream>>>(xb, pb, fb, Acat, Bcat, alpha, beta, theta);

  // GEMM3: 4096x512, K=4096 split 4 ways; 1D grid 512 x 512 threads
  gemm3<<<512, 512, 0, stream>>>(Acat, Bcat, part);

  // reduce z=0..4 -> out (4 q-chunks per tile, one per block)
  reduce4<<<512, 512, 0, stream>>>(part, out);
}